// Round 1
// baseline (376.195 us; speedup 1.0000x reference)
//
#include <hip/hip_runtime.h>
#include <math.h>

// B=8, C=512, H=W=64, N=4096. All-fp32 inputs; bf16 MFMA compute internally.
typedef unsigned short u16;
typedef __attribute__((ext_vector_type(8))) short bf16x8;  // 8 bf16 = 4 VGPRs
typedef __attribute__((ext_vector_type(4))) float f32x4;

#define BATCH 8
#define CDIM 512
#define NDIM 4096
#define LDSTRIDE 40   // 32 bf16 + 8 pad (=16B) -> 80B row stride, 2-way LDS conflicts only (free)

__device__ inline float bf2f(u16 u) {
    unsigned int x = ((unsigned int)u) << 16;
    return __uint_as_float(x);
}
__device__ inline u16 f2bf(float f) {  // round-to-nearest-even
    unsigned int u = __float_as_uint(f);
    unsigned int r = u + 0x7fffu + ((u >> 16) & 1u);
    return (u16)(r >> 16);
}

// ---------------------------------------------------------------------------
// Shared MFMA GEMM core: C[128x128] tile = A(rows m, k-contig) x B(rows n, k-contig)^T
// 256 threads = 4 waves in 2x2; each wave does 4x4 grid of 16x16x32 MFMAs.
// ---------------------------------------------------------------------------
__device__ inline void gemm_core(const u16* __restrict__ A, const u16* __restrict__ B,
                                 int lda, int ldb, int K,
                                 u16* As, u16* Bs, f32x4 (&acc)[4][4]) {
    const int t = threadIdx.x;
    const int wave = t >> 6, lane = t & 63;
    const int wm = (wave & 1) * 64, wn = (wave >> 1) * 64;
    const int lr = lane & 15, lq = lane >> 4;
    const int srow = t >> 2;          // 0..63
    const int schunk = (t & 3) * 8;   // 0,8,16,24 (bf16 elements)

    for (int k0 = 0; k0 < K; k0 += 32) {
        __syncthreads();
        // stage A rows [0,128) and B rows [0,128), 32 k-elements each (16B/lane x 2 rows)
        *(uint4*)(As + srow * LDSTRIDE + schunk) =
            *(const uint4*)(A + (size_t)srow * lda + k0 + schunk);
        *(uint4*)(As + (srow + 64) * LDSTRIDE + schunk) =
            *(const uint4*)(A + (size_t)(srow + 64) * lda + k0 + schunk);
        *(uint4*)(Bs + srow * LDSTRIDE + schunk) =
            *(const uint4*)(B + (size_t)srow * ldb + k0 + schunk);
        *(uint4*)(Bs + (srow + 64) * LDSTRIDE + schunk) =
            *(const uint4*)(B + (size_t)(srow + 64) * ldb + k0 + schunk);
        __syncthreads();

        bf16x8 af[4], bfr[4];
#pragma unroll
        for (int i = 0; i < 4; i++)
            af[i] = *(const bf16x8*)(As + (wm + i * 16 + lr) * LDSTRIDE + lq * 8);
#pragma unroll
        for (int i = 0; i < 4; i++)
            bfr[i] = *(const bf16x8*)(Bs + (wn + i * 16 + lr) * LDSTRIDE + lq * 8);
#pragma unroll
        for (int i = 0; i < 4; i++)
#pragma unroll
            for (int j = 0; j < 4; j++)
                acc[i][j] = __builtin_amdgcn_mfma_f32_16x16x32_bf16(af[i], bfr[j], acc[i][j], 0, 0, 0);
    }
}

// ---------------------------------------------------------------------------
// K0a: convert Wq/Wk/Wv fp32 -> bf16 into Wb[3][512][512]
// ---------------------------------------------------------------------------
__global__ __launch_bounds__(256) void convw(const float* __restrict__ Wq,
                                             const float* __restrict__ Wk,
                                             const float* __restrict__ Wv,
                                             u16* __restrict__ Wb) {
    int i = blockIdx.x * 256 + threadIdx.x;     // < 3*2^18
    int w = i >> 18;
    int j = i & 262143;
    const float* s = (w == 0) ? Wq : (w == 1) ? Wk : Wv;
    Wb[i] = f2bf(s[j]);
}

// ---------------------------------------------------------------------------
// K0b: transpose+convert x[b][c][n] fp32 -> xT[b][n][c] bf16
// ---------------------------------------------------------------------------
__global__ __launch_bounds__(256) void transpose_x(const float* __restrict__ x,
                                                   u16* __restrict__ xT) {
    __shared__ float tile[32][33];
    int n0 = blockIdx.x * 32, c0 = blockIdx.y * 32, b = blockIdx.z;
    int tx = threadIdx.x, ty = threadIdx.y;   // 32 x 8
    const float* xb = x + (size_t)b * CDIM * NDIM;
    u16* xTb = xT + (size_t)b * NDIM * CDIM;
#pragma unroll
    for (int j = 0; j < 4; j++)
        tile[ty + j * 8][tx] = xb[(size_t)(c0 + ty + j * 8) * NDIM + n0 + tx];
    __syncthreads();
#pragma unroll
    for (int j = 0; j < 4; j++)
        xTb[(size_t)(n0 + ty + j * 8) * CDIM + c0 + tx] = f2bf(tile[tx][ty + j * 8]);
}

// ---------------------------------------------------------------------------
// K1: QKV GEMM. blockIdx.z = b*3+w. D[o][n] = sum_c W[o][c] * xT[n][c].
// w=0 -> Q[b][o][n], w=1 -> K[b][o][n], w=2 -> VT[b][n][o] (pre-transposed for MV GEMM)
// ---------------------------------------------------------------------------
__global__ __launch_bounds__(256) void qkv_mfma(const u16* __restrict__ Wb,
                                                const u16* __restrict__ xT,
                                                u16* __restrict__ Qb, u16* __restrict__ Kb,
                                                u16* __restrict__ VT) {
    __shared__ __align__(16) u16 As[128 * LDSTRIDE];
    __shared__ __align__(16) u16 Bs[128 * LDSTRIDE];
    int bz = blockIdx.z;
    int b = bz / 3, w = bz % 3;
    int m0 = blockIdx.y * 128, n0 = blockIdx.x * 128;
    const u16* A = Wb + ((size_t)w << 18) + (size_t)m0 * CDIM;
    const u16* B = xT + (size_t)b * NDIM * CDIM + (size_t)n0 * CDIM;

    f32x4 acc[4][4];
#pragma unroll
    for (int i = 0; i < 4; i++)
#pragma unroll
        for (int j = 0; j < 4; j++) acc[i][j] = (f32x4){0.f, 0.f, 0.f, 0.f};

    gemm_core(A, B, CDIM, CDIM, CDIM, As, Bs, acc);

    int wave = threadIdx.x >> 6, lane = threadIdx.x & 63;
    int wm = (wave & 1) * 64, wn = (wave >> 1) * 64;
    int lr = lane & 15, lq = lane >> 4;

    if (w < 2) {
        u16* O = (w ? Kb : Qb) + (size_t)b * CDIM * NDIM;
#pragma unroll
        for (int mt = 0; mt < 4; mt++)
#pragma unroll
            for (int nt = 0; nt < 4; nt++) {
                int r0 = m0 + wm + mt * 16 + lq * 4;
                int cc = n0 + wn + nt * 16 + lr;
#pragma unroll
                for (int i = 0; i < 4; i++)
                    O[(size_t)(r0 + i) * NDIM + cc] = f2bf(acc[mt][nt][i]);
            }
    } else {
        u16* O = VT + (size_t)b * NDIM * CDIM;
#pragma unroll
        for (int mt = 0; mt < 4; mt++)
#pragma unroll
            for (int nt = 0; nt < 4; nt++) {
                int r0 = m0 + wm + mt * 16 + lq * 4;   // o, 4 consecutive
                int cc = n0 + wn + nt * 16 + lr;        // n
                ushort4 pk;
                pk.x = f2bf(acc[mt][nt][0]); pk.y = f2bf(acc[mt][nt][1]);
                pk.z = f2bf(acc[mt][nt][2]); pk.w = f2bf(acc[mt][nt][3]);
                *(ushort4*)(O + (size_t)cc * CDIM + r0) = pk;
            }
    }
}

// ---------------------------------------------------------------------------
// K2: 1/||row||_2 for Q and K rows (over N=4096). blockIdx.x = b*512+c, y=0:Q y=1:K
// ---------------------------------------------------------------------------
__global__ __launch_bounds__(256) void rownorm(const u16* __restrict__ Qb,
                                               const u16* __restrict__ Kb,
                                               float* __restrict__ rq, float* __restrict__ rk) {
    __shared__ float red[4];
    int row = blockIdx.x;
    const u16* p = (blockIdx.y ? Kb : Qb) + (size_t)row * NDIM;
    float s = 0.f;
    for (int base = threadIdx.x * 8; base < NDIM; base += 2048) {
        uint4 u = *(const uint4*)(p + base);
        const u16* q = (const u16*)&u;
#pragma unroll
        for (int j = 0; j < 8; j++) { float f = bf2f(q[j]); s += f * f; }
    }
    for (int o = 32; o; o >>= 1) s += __shfl_down(s, o);
    if ((threadIdx.x & 63) == 0) red[threadIdx.x >> 6] = s;
    __syncthreads();
    if (threadIdx.x == 0) {
        float tot = red[0] + red[1] + red[2] + red[3];
        (blockIdx.y ? rk : rq)[row] = 1.f / sqrtf(tot);
    }
}

// ---------------------------------------------------------------------------
// K3: T[b][d][c] = (Q[c]·K[d]) * rq[c] * rk[d]   (cosine sim, stored transposed)
// A = Q rows (m=c), B = K rows (n=d); epilogue writes transposed as float4.
// ---------------------------------------------------------------------------
__global__ __launch_bounds__(256) void qk_mfma(const u16* __restrict__ Qb,
                                               const u16* __restrict__ Kb,
                                               const float* __restrict__ rq,
                                               const float* __restrict__ rk,
                                               float* __restrict__ T) {
    __shared__ __align__(16) u16 As[128 * LDSTRIDE];
    __shared__ __align__(16) u16 Bs[128 * LDSTRIDE];
    int b = blockIdx.z;
    int m0 = blockIdx.y * 128, n0 = blockIdx.x * 128;
    const u16* A = Qb + (size_t)b * CDIM * NDIM + (size_t)m0 * NDIM;
    const u16* B = Kb + (size_t)b * CDIM * NDIM + (size_t)n0 * NDIM;

    f32x4 acc[4][4];
#pragma unroll
    for (int i = 0; i < 4; i++)
#pragma unroll
        for (int j = 0; j < 4; j++) acc[i][j] = (f32x4){0.f, 0.f, 0.f, 0.f};

    gemm_core(A, B, NDIM, NDIM, NDIM, As, Bs, acc);

    int wave = threadIdx.x >> 6, lane = threadIdx.x & 63;
    int wm = (wave & 1) * 64, wn = (wave >> 1) * 64;
    int lr = lane & 15, lq = lane >> 4;
    const float* rqb = rq + b * CDIM;
    const float* rkb = rk + b * CDIM;
    float* Tb = T + (size_t)b * CDIM * CDIM;
#pragma unroll
    for (int mt = 0; mt < 4; mt++)
#pragma unroll
        for (int nt = 0; nt < 4; nt++) {
            int cbase = m0 + wm + mt * 16 + lq * 4;   // c, 4 consecutive
            int d = n0 + wn + nt * 16 + lr;
            float rkd = rkb[d];
            float4 v;
            v.x = acc[mt][nt][0] * rqb[cbase + 0] * rkd;
            v.y = acc[mt][nt][1] * rqb[cbase + 1] * rkd;
            v.z = acc[mt][nt][2] * rqb[cbase + 2] * rkd;
            v.w = acc[mt][nt][3] * rqb[cbase + 3] * rkd;
            *(float4*)(Tb + (size_t)d * CDIM + cbase) = v;
        }
}

// ---------------------------------------------------------------------------
// K4: per row of T (= column of S): a=1-v; m=max(a); b=1-4*a/(m+eps); softmax.
// In-place. blockIdx.x = b*512 + d. 256 threads, 2 elements each.
// ---------------------------------------------------------------------------
__global__ __launch_bounds__(256) void softmax_col(float* __restrict__ T) {
    __shared__ float red[4];
    float* p = T + (size_t)blockIdx.x * CDIM;
    int t = threadIdx.x;
    float v0 = p[t], v1 = p[t + 256];
    float a0 = 1.f - v0, a1 = 1.f - v1;
    float m = fmaxf(a0, a1);
    for (int o = 32; o; o >>= 1) m = fmaxf(m, __shfl_down(m, o));
    if ((t & 63) == 0) red[t >> 6] = m;
    __syncthreads();
    m = fmaxf(fmaxf(red[0], red[1]), fmaxf(red[2], red[3])) + 1e-6f;
    __syncthreads();   // red about to be reused
    float inv = 4.f / m;   // /(m) then /0.25
    float b0 = 1.f - a0 * inv, b1 = 1.f - a1 * inv;
    float e0 = __expf(b0), e1 = __expf(b1);
    float s = e0 + e1;
    for (int o = 32; o; o >>= 1) s += __shfl_down(s, o);
    if ((t & 63) == 0) red[t >> 6] = s;
    __syncthreads();
    s = red[0] + red[1] + red[2] + red[3];
    float r = 1.f / s;
    p[t] = e0 * r;
    p[t + 256] = e1 * r;
}

// ---------------------------------------------------------------------------
// K5: rs[b][c] = 1/(sum_d T'[b][d][c] + eps)   (row-L1 of M = column-sum of T')
// ---------------------------------------------------------------------------
__global__ __launch_bounds__(256) void colsum(const float* __restrict__ T,
                                              float* __restrict__ rs) {
    int b = blockIdx.x;
    int c = blockIdx.y * 256 + threadIdx.x;
    const float* p = T + (size_t)b * CDIM * CDIM + c;
    float s = 0.f;
    for (int d = 0; d < CDIM; d++) s += p[(size_t)d * CDIM];
    rs[b * CDIM + c] = 1.f / (s + 1e-6f);
}

// ---------------------------------------------------------------------------
// K6a: Mb[b][c][d] = bf16( T'[b][d][c] * rs[b][c] )   (transpose + scale + cvt)
// ---------------------------------------------------------------------------
__global__ __launch_bounds__(256) void mscale(const float* __restrict__ T,
                                              const float* __restrict__ rs,
                                              u16* __restrict__ Mb) {
    __shared__ float tile[32][33];
    int b = blockIdx.z;
    int d0 = blockIdx.x * 32, c0 = blockIdx.y * 32;
    int tx = threadIdx.x, ty = threadIdx.y;
    const float* Tb = T + (size_t)b * CDIM * CDIM;
#pragma unroll
    for (int j = 0; j < 4; j++)
        tile[ty + j * 8][tx] = Tb[(size_t)(d0 + ty + j * 8) * CDIM + c0 + tx];
    __syncthreads();
    const float* rsb = rs + b * CDIM;
    u16* Mbb = Mb + (size_t)b * CDIM * CDIM;
#pragma unroll
    for (int j = 0; j < 4; j++) {
        int c = c0 + ty + j * 8;
        Mbb[(size_t)c * CDIM + d0 + tx] = f2bf(tile[tx][ty + j * 8] * rsb[c]);
    }
}

// ---------------------------------------------------------------------------
// K6: out[b][c][n] = x + gamma * sum_d Mb[c][d] * VT[n][d]
// ---------------------------------------------------------------------------
__global__ __launch_bounds__(256) void out_mfma(const u16* __restrict__ Mb,
                                                const u16* __restrict__ VT,
                                                const float* __restrict__ x,
                                                const float* __restrict__ gamma,
                                                float* __restrict__ y) {
    __shared__ __align__(16) u16 As[128 * LDSTRIDE];
    __shared__ __align__(16) u16 Bs[128 * LDSTRIDE];
    int b = blockIdx.z;
    int m0 = blockIdx.y * 128, n0 = blockIdx.x * 128;
    const u16* A = Mb + (size_t)b * CDIM * CDIM + (size_t)m0 * CDIM;
    const u16* B = VT + (size_t)b * NDIM * CDIM + (size_t)n0 * CDIM;

    f32x4 acc[4][4];
#pragma unroll
    for (int i = 0; i < 4; i++)
#pragma unroll
        for (int j = 0; j < 4; j++) acc[i][j] = (f32x4){0.f, 0.f, 0.f, 0.f};

    gemm_core(A, B, CDIM, CDIM, CDIM, As, Bs, acc);

    int wave = threadIdx.x >> 6, lane = threadIdx.x & 63;
    int wm = (wave & 1) * 64, wn = (wave >> 1) * 64;
    int lr = lane & 15, lq = lane >> 4;
    float g = *gamma;
    const float* xb = x + (size_t)b * CDIM * NDIM;
    float* yb = y + (size_t)b * CDIM * NDIM;
#pragma unroll
    for (int mt = 0; mt < 4; mt++)
#pragma unroll
        for (int nt = 0; nt < 4; nt++) {
            int r0 = m0 + wm + mt * 16 + lq * 4;
            int cc = n0 + wn + nt * 16 + lr;
#pragma unroll
            for (int i = 0; i < 4; i++) {
                size_t idx = (size_t)(r0 + i) * NDIM + cc;
                yb[idx] = xb[idx] + g * acc[mt][nt][i];
            }
        }
}

// ---------------------------------------------------------------------------
extern "C" void kernel_launch(void* const* d_in, const int* in_sizes, int n_in,
                              void* d_out, int out_size, void* d_ws, size_t ws_size,
                              hipStream_t stream) {
    (void)in_sizes; (void)n_in; (void)out_size; (void)ws_size;
    const float* x     = (const float*)d_in[0];
    const float* Wq    = (const float*)d_in[1];
    const float* Wk    = (const float*)d_in[2];
    const float* Wv    = (const float*)d_in[3];
    const float* gamma = (const float*)d_in[4];
    float* y = (float*)d_out;

    char* ws = (char*)d_ws;
    // xT occupies [0, 32MB) and is dead after qkv_mfma; T/Mb/rs alias into it.
    u16*   xT = (u16*)(ws);                      // 32 MB  [B][4096][512] bf16
    float* T  = (float*)(ws);                    //  8 MB  [B][512][512] fp32 (alias)
    u16*   Mb = (u16*)(ws + 8388608);            //  4 MB  [B][512][512] bf16 (alias)
    float* rs = (float*)(ws + 12582912);         // 16 KB  (alias)
    u16*   Wb = (u16*)(ws + 33554432);           // 1.5 MB [3][512][512] bf16
    float* rq = (float*)(ws + 35127296);         // 16 KB
    float* rk = (float*)(ws + 35143680);         // 16 KB
    u16*   Qb = (u16*)(ws + 35160064);           // 32 MB  [B][512][4096] bf16
    u16*   Kb = (u16*)(ws + 68714496);           // 32 MB
    u16*   VT = (u16*)(ws + 102268928);          // 32 MB  [B][4096][512] bf16

    convw<<<3072, 256, 0, stream>>>(Wq, Wk, Wv, Wb);
    transpose_x<<<dim3(128, 16, 8), dim3(32, 8), 0, stream>>>(x, xT);
    qkv_mfma<<<dim3(32, 4, 24), 256, 0, stream>>>(Wb, xT, Qb, Kb, VT);
    rownorm<<<dim3(4096, 2), 256, 0, stream>>>(Qb, Kb, rq, rk);
    qk_mfma<<<dim3(4, 4, 8), 256, 0, stream>>>(Qb, Kb, rq, rk, T);
    softmax_col<<<4096, 256, 0, stream>>>(T);
    colsum<<<dim3(8, 2), 256, 0, stream>>>(T, rs);
    mscale<<<dim3(16, 16, 8), dim3(32, 8), 0, stream>>>(T, rs, Mb);
    out_mfma<<<dim3(32, 4, 8), 256, 0, stream>>>(Mb, VT, x, gamma, y);
}

// Round 2
// 324.313 us; speedup vs baseline: 1.1600x; 1.1600x over previous
//
#include <hip/hip_runtime.h>
#include <math.h>

// B=8, C=512, H=W=64, N=4096. All-fp32 inputs; bf16 MFMA compute internally.
typedef unsigned short u16;
typedef __attribute__((ext_vector_type(8))) short bf16x8;  // 8 bf16 = 4 VGPRs
typedef __attribute__((ext_vector_type(4))) float f32x4;

#define BATCH 8
#define CDIM 512
#define NDIM 4096
#define BK 32   // K-tile (bf16 elements); LDS rows are unpadded 64B (global_load_lds requirement)

__device__ inline float bf2f(u16 u) {
    unsigned int x = ((unsigned int)u) << 16;
    return __uint_as_float(x);
}
__device__ inline u16 f2bf(float f) {  // round-to-nearest-even
    unsigned int u = __float_as_uint(f);
    unsigned int r = u + 0x7fffu + ((u >> 16) & 1u);
    return (u16)(r >> 16);
}

// async 16B/lane global->LDS DMA; LDS dest = uniform base + lane*16
#define GLOAD_LDS(g, l)                                                        \
    __builtin_amdgcn_global_load_lds(                                          \
        (const __attribute__((address_space(1))) void*)(g),                    \
        (__attribute__((address_space(3))) void*)(l), 16, 0, 0)

// ---------------------------------------------------------------------------
// Shared MFMA GEMM core: C[128x128] tile = A(rows m, k-contig) x B(rows n, k-contig)^T
// 256 threads = 4 waves in 2x2; each wave does 4x4 grid of 16x16x32 MFMAs.
// Staging via global_load_lds (16B/lane): wave w stages rows [32w,32w+32) of A and B.
// LDS layout [128][BK] unpadded: fragment ds_read_b128 sweep is exactly 1KB
// contiguous per wave -> minimal (conflict-free) bank schedule.
// ---------------------------------------------------------------------------
__device__ inline void gemm_core(const u16* __restrict__ A, const u16* __restrict__ B,
                                 int lda, int ldb, int K,
                                 u16* As, u16* Bs, f32x4 (&acc)[4][4]) {
    const int t = threadIdx.x;
    const int wave = t >> 6, lane = t & 63;
    const int wm = (wave & 1) * 64, wn = (wave >> 1) * 64;
    const int lr = lane & 15, lq = lane >> 4;

    const int srow = wave * 32 + (lane >> 2);   // staging row (j=0)
    const int sk = (lane & 3) * 8;              // k-chunk (bf16 elems)
    const u16* Ap0 = A + (size_t)srow * lda + sk;
    const u16* Ap1 = Ap0 + (size_t)16 * lda;
    const u16* Bp0 = B + (size_t)srow * ldb + sk;
    const u16* Bp1 = Bp0 + (size_t)16 * ldb;
    u16* As0 = As + wave * 32 * BK;             // wave-uniform LDS bases
    u16* As1 = As0 + 16 * BK;
    u16* Bs0 = Bs + wave * 32 * BK;
    u16* Bs1 = Bs0 + 16 * BK;

    for (int k0 = 0; k0 < K; k0 += BK) {
        __syncthreads();
        GLOAD_LDS(Ap0 + k0, As0);
        GLOAD_LDS(Ap1 + k0, As1);
        GLOAD_LDS(Bp0 + k0, Bs0);
        GLOAD_LDS(Bp1 + k0, Bs1);
        __syncthreads();

        bf16x8 af[4], bfr[4];
#pragma unroll
        for (int i = 0; i < 4; i++)
            af[i] = *(const bf16x8*)(As + (wm + i * 16 + lr) * BK + lq * 8);
#pragma unroll
        for (int i = 0; i < 4; i++)
            bfr[i] = *(const bf16x8*)(Bs + (wn + i * 16 + lr) * BK + lq * 8);
#pragma unroll
        for (int i = 0; i < 4; i++)
#pragma unroll
            for (int j = 0; j < 4; j++)
                acc[i][j] = __builtin_amdgcn_mfma_f32_16x16x32_bf16(af[i], bfr[j], acc[i][j], 0, 0, 0);
    }
}

// ---------------------------------------------------------------------------
// K0a: convert Wq/Wk/Wv fp32 -> bf16 into Wb[3][512][512]
// ---------------------------------------------------------------------------
__global__ __launch_bounds__(256) void convw(const float* __restrict__ Wq,
                                             const float* __restrict__ Wk,
                                             const float* __restrict__ Wv,
                                             u16* __restrict__ Wb) {
    int i = blockIdx.x * 256 + threadIdx.x;     // < 3*2^18
    int w = i >> 18;
    int j = i & 262143;
    const float* s = (w == 0) ? Wq : (w == 1) ? Wk : Wv;
    Wb[i] = f2bf(s[j]);
}

// ---------------------------------------------------------------------------
// K0b: transpose+convert x[b][c][n] fp32 -> xT[b][n][c] bf16. 64x64 tiles,
// 256 threads; 16B bf16 stores.
// ---------------------------------------------------------------------------
__global__ __launch_bounds__(256) void transpose_x(const float* __restrict__ x,
                                                   u16* __restrict__ xT) {
    __shared__ float tile[64][65];
    int n0 = blockIdx.x * 64, c0 = blockIdx.y * 64, b = blockIdx.z;
    int t = threadIdx.x;
    int tx = t & 63, ty = t >> 6;   // ty 0..3
    const float* xb = x + (size_t)b * CDIM * NDIM;
#pragma unroll
    for (int j = 0; j < 16; j++)
        tile[ty + j * 4][tx] = xb[(size_t)(c0 + ty + j * 4) * NDIM + n0 + tx];
    __syncthreads();
    u16* xTb = xT + (size_t)b * NDIM * CDIM;
    int r = t >> 3;          // 0..31
    int cg = (t & 7) * 8;
#pragma unroll
    for (int j = 0; j < 2; j++) {
        int rr = r + j * 32;
        u16 tmp[8];
#pragma unroll
        for (int i = 0; i < 8; i++) tmp[i] = f2bf(tile[cg + i][rr]);
        *(uint4*)(xTb + (size_t)(n0 + rr) * CDIM + c0 + cg) = *(uint4*)tmp;
    }
}

// ---------------------------------------------------------------------------
// K1: QKV GEMM. blockIdx.z = b*3+w. D[o][n] = sum_c W[o][c] * xT[n][c].
// w=0 -> Q[b][o][n], w=1 -> K[b][o][n], w=2 -> VT[b][n][o] (pre-transposed for MV GEMM)
// ---------------------------------------------------------------------------
__global__ __launch_bounds__(256) void qkv_mfma(const u16* __restrict__ Wb,
                                                const u16* __restrict__ xT,
                                                u16* __restrict__ Qb, u16* __restrict__ Kb,
                                                u16* __restrict__ VT) {
    __shared__ __align__(16) u16 As[128 * BK];
    __shared__ __align__(16) u16 Bs[128 * BK];
    int bz = blockIdx.z;
    int b = bz / 3, w = bz % 3;
    int m0 = blockIdx.y * 128, n0 = blockIdx.x * 128;
    const u16* A = Wb + ((size_t)w << 18) + (size_t)m0 * CDIM;
    const u16* B = xT + (size_t)b * NDIM * CDIM + (size_t)n0 * CDIM;

    f32x4 acc[4][4];
#pragma unroll
    for (int i = 0; i < 4; i++)
#pragma unroll
        for (int j = 0; j < 4; j++) acc[i][j] = (f32x4){0.f, 0.f, 0.f, 0.f};

    gemm_core(A, B, CDIM, CDIM, CDIM, As, Bs, acc);

    int wave = threadIdx.x >> 6, lane = threadIdx.x & 63;
    int wm = (wave & 1) * 64, wn = (wave >> 1) * 64;
    int lr = lane & 15, lq = lane >> 4;

    if (w < 2) {
        u16* O = (w ? Kb : Qb) + (size_t)b * CDIM * NDIM;
#pragma unroll
        for (int mt = 0; mt < 4; mt++)
#pragma unroll
            for (int nt = 0; nt < 4; nt++) {
                int r0 = m0 + wm + mt * 16 + lq * 4;
                int cc = n0 + wn + nt * 16 + lr;
#pragma unroll
                for (int i = 0; i < 4; i++)
                    O[(size_t)(r0 + i) * NDIM + cc] = f2bf(acc[mt][nt][i]);
            }
    } else {
        u16* O = VT + (size_t)b * NDIM * CDIM;
#pragma unroll
        for (int mt = 0; mt < 4; mt++)
#pragma unroll
            for (int nt = 0; nt < 4; nt++) {
                int r0 = m0 + wm + mt * 16 + lq * 4;   // o, 4 consecutive
                int cc = n0 + wn + nt * 16 + lr;        // n
                ushort4 pk;
                pk.x = f2bf(acc[mt][nt][0]); pk.y = f2bf(acc[mt][nt][1]);
                pk.z = f2bf(acc[mt][nt][2]); pk.w = f2bf(acc[mt][nt][3]);
                *(ushort4*)(O + (size_t)cc * CDIM + r0) = pk;
            }
    }
}

// ---------------------------------------------------------------------------
// K2: 1/||row||_2 for Q and K rows (over N=4096). blockIdx.x = b*512+c, y=0:Q y=1:K
// ---------------------------------------------------------------------------
__global__ __launch_bounds__(256) void rownorm(const u16* __restrict__ Qb,
                                               const u16* __restrict__ Kb,
                                               float* __restrict__ rq, float* __restrict__ rk) {
    __shared__ float red[4];
    int row = blockIdx.x;
    const u16* p = (blockIdx.y ? Kb : Qb) + (size_t)row * NDIM;
    float s = 0.f;
    for (int base = threadIdx.x * 8; base < NDIM; base += 2048) {
        uint4 u = *(const uint4*)(p + base);
        const u16* q = (const u16*)&u;
#pragma unroll
        for (int j = 0; j < 8; j++) { float f = bf2f(q[j]); s += f * f; }
    }
    for (int o = 32; o; o >>= 1) s += __shfl_down(s, o);
    if ((threadIdx.x & 63) == 0) red[threadIdx.x >> 6] = s;
    __syncthreads();
    if (threadIdx.x == 0) {
        float tot = red[0] + red[1] + red[2] + red[3];
        (blockIdx.y ? rk : rq)[row] = 1.f / sqrtf(tot);
    }
}

// ---------------------------------------------------------------------------
// K3: split-K Gram GEMM. blockIdx.z = b*4 + s; K window [s*1024,(s+1)*1024).
// Tpart[s][b][d][c] = partial( Q[c] . K[d] )   (raw dots; scaling deferred)
// ---------------------------------------------------------------------------
__global__ __launch_bounds__(256) void qk_part(const u16* __restrict__ Qb,
                                               const u16* __restrict__ Kb,
                                               float* __restrict__ Tpart) {
    __shared__ __align__(16) u16 As[128 * BK];
    __shared__ __align__(16) u16 Bs[128 * BK];
    int bz = blockIdx.z;
    int b = bz >> 2, s = bz & 3;
    int m0 = blockIdx.y * 128, n0 = blockIdx.x * 128;
    const u16* A = Qb + (size_t)b * CDIM * NDIM + (size_t)m0 * NDIM + s * 1024;
    const u16* B = Kb + (size_t)b * CDIM * NDIM + (size_t)n0 * NDIM + s * 1024;

    f32x4 acc[4][4];
#pragma unroll
    for (int i = 0; i < 4; i++)
#pragma unroll
        for (int j = 0; j < 4; j++) acc[i][j] = (f32x4){0.f, 0.f, 0.f, 0.f};

    gemm_core(A, B, NDIM, NDIM, 1024, As, Bs, acc);

    int wave = threadIdx.x >> 6, lane = threadIdx.x & 63;
    int wm = (wave & 1) * 64, wn = (wave >> 1) * 64;
    int lr = lane & 15, lq = lane >> 4;
    float* Tb = Tpart + ((size_t)(s * 8 + b) * CDIM) * CDIM;
#pragma unroll
    for (int mt = 0; mt < 4; mt++)
#pragma unroll
        for (int nt = 0; nt < 4; nt++) {
            int cbase = m0 + wm + mt * 16 + lq * 4;   // c, 4 consecutive
            int d = n0 + wn + nt * 16 + lr;
            float4 v;
            v.x = acc[mt][nt][0]; v.y = acc[mt][nt][1];
            v.z = acc[mt][nt][2]; v.w = acc[mt][nt][3];
            *(float4*)(Tb + (size_t)d * CDIM + cbase) = v;
        }
}

// ---------------------------------------------------------------------------
// K4: fused split-K reduce + cosine scale + column softmax.
// Row (b,d): v[c] = (sum_s Tpart[s]) * rq[c]*rk[d]; a=1-v; m=max(a)+eps;
// b=1-4a/m; softmax over c. Writes Tf (aliases Tpart[0] 1:1 by row).
// ---------------------------------------------------------------------------
__global__ __launch_bounds__(256) void softmax_col(const float* __restrict__ Tpart,
                                                   const float* __restrict__ rq,
                                                   const float* __restrict__ rk,
                                                   float* __restrict__ Tf) {
    __shared__ float red[4];
    int row = blockIdx.x;            // b*512 + d
    int b = row >> 9;
    const float* p = Tpart + (size_t)row * CDIM;
    float* o = Tf + (size_t)row * CDIM;
    int t = threadIdx.x;
    float rkd = rk[row];
    float q0 = rq[(b << 9) + t], q1 = rq[(b << 9) + t + 256];
    const size_t SS = (size_t)8 * CDIM * CDIM;   // per-split stride (floats)
    float v0 = (p[t] + p[t + SS] + p[t + 2 * SS] + p[t + 3 * SS]) * q0 * rkd;
    float v1 = (p[t + 256] + p[t + 256 + SS] + p[t + 256 + 2 * SS] + p[t + 256 + 3 * SS]) * q1 * rkd;
    float a0 = 1.f - v0, a1 = 1.f - v1;
    float m = fmaxf(a0, a1);
    for (int of = 32; of; of >>= 1) m = fmaxf(m, __shfl_down(m, of));
    if ((t & 63) == 0) red[t >> 6] = m;
    __syncthreads();
    m = fmaxf(fmaxf(red[0], red[1]), fmaxf(red[2], red[3])) + 1e-6f;
    __syncthreads();   // red about to be reused
    float inv = 4.f / m;   // /(m) then /0.25
    float b0 = 1.f - a0 * inv, b1 = 1.f - a1 * inv;
    float e0 = __expf(b0), e1 = __expf(b1);
    float s = e0 + e1;
    for (int of = 32; of; of >>= 1) s += __shfl_down(s, of);
    if ((t & 63) == 0) red[t >> 6] = s;
    __syncthreads();
    s = red[0] + red[1] + red[2] + red[3];
    float r = 1.f / s;
    o[t] = e0 * r;
    o[t + 256] = e1 * r;
}

// ---------------------------------------------------------------------------
// K5: rs[b][c] = 1/(sum_d Tf[b][d][c] + eps)   (row-L1 of M = column-sum of Tf)
// ---------------------------------------------------------------------------
__global__ __launch_bounds__(256) void colsum(const float* __restrict__ T,
                                              float* __restrict__ rs) {
    int b = blockIdx.x;
    int c = blockIdx.y * 256 + threadIdx.x;
    const float* p = T + (size_t)b * CDIM * CDIM + c;
    float s = 0.f;
    for (int d = 0; d < CDIM; d++) s += p[(size_t)d * CDIM];
    rs[b * CDIM + c] = 1.f / (s + 1e-6f);
}

// ---------------------------------------------------------------------------
// K6a: Mb[b][c][d] = bf16( Tf[b][d][c] * rs[b][c] )   (transpose + scale + cvt)
// ---------------------------------------------------------------------------
__global__ __launch_bounds__(256) void mscale(const float* __restrict__ T,
                                              const float* __restrict__ rs,
                                              u16* __restrict__ Mb) {
    __shared__ float tile[32][33];
    int b = blockIdx.z;
    int d0 = blockIdx.x * 32, c0 = blockIdx.y * 32;
    int tx = threadIdx.x, ty = threadIdx.y;
    const float* Tb = T + (size_t)b * CDIM * CDIM;
#pragma unroll
    for (int j = 0; j < 4; j++)
        tile[ty + j * 8][tx] = Tb[(size_t)(d0 + ty + j * 8) * CDIM + c0 + tx];
    __syncthreads();
    const float* rsb = rs + b * CDIM;
    u16* Mbb = Mb + (size_t)b * CDIM * CDIM;
#pragma unroll
    for (int j = 0; j < 4; j++) {
        int c = c0 + ty + j * 8;
        Mbb[(size_t)c * CDIM + d0 + tx] = f2bf(tile[tx][ty + j * 8] * rsb[c]);
    }
}

// ---------------------------------------------------------------------------
// K6: out[b][c][n] = x + gamma * sum_d Mb[c][d] * VT[n][d]
// ---------------------------------------------------------------------------
__global__ __launch_bounds__(256) void out_mfma(const u16* __restrict__ Mb,
                                                const u16* __restrict__ VT,
                                                const float* __restrict__ x,
                                                const float* __restrict__ gamma,
                                                float* __restrict__ y) {
    __shared__ __align__(16) u16 As[128 * BK];
    __shared__ __align__(16) u16 Bs[128 * BK];
    int b = blockIdx.z;
    int m0 = blockIdx.y * 128, n0 = blockIdx.x * 128;
    const u16* A = Mb + (size_t)b * CDIM * CDIM + (size_t)m0 * CDIM;
    const u16* B = VT + (size_t)b * NDIM * CDIM + (size_t)n0 * CDIM;

    f32x4 acc[4][4];
#pragma unroll
    for (int i = 0; i < 4; i++)
#pragma unroll
        for (int j = 0; j < 4; j++) acc[i][j] = (f32x4){0.f, 0.f, 0.f, 0.f};

    gemm_core(A, B, CDIM, CDIM, CDIM, As, Bs, acc);

    int wave = threadIdx.x >> 6, lane = threadIdx.x & 63;
    int wm = (wave & 1) * 64, wn = (wave >> 1) * 64;
    int lr = lane & 15, lq = lane >> 4;
    float g = *gamma;
    const float* xb = x + (size_t)b * CDIM * NDIM;
    float* yb = y + (size_t)b * CDIM * NDIM;
#pragma unroll
    for (int mt = 0; mt < 4; mt++)
#pragma unroll
        for (int nt = 0; nt < 4; nt++) {
            int r0 = m0 + wm + mt * 16 + lq * 4;
            int cc = n0 + wn + nt * 16 + lr;
#pragma unroll
            for (int i = 0; i < 4; i++) {
                size_t idx = (size_t)(r0 + i) * NDIM + cc;
                yb[idx] = xb[idx] + g * acc[mt][nt][i];
            }
        }
}

// ---------------------------------------------------------------------------
extern "C" void kernel_launch(void* const* d_in, const int* in_sizes, int n_in,
                              void* d_out, int out_size, void* d_ws, size_t ws_size,
                              hipStream_t stream) {
    (void)in_sizes; (void)n_in; (void)out_size; (void)ws_size;
    const float* x     = (const float*)d_in[0];
    const float* Wq    = (const float*)d_in[1];
    const float* Wk    = (const float*)d_in[2];
    const float* Wv    = (const float*)d_in[3];
    const float* gamma = (const float*)d_in[4];
    float* y = (float*)d_out;

    char* ws = (char*)d_ws;
    // [0,32MB): xT (dead after qkv) -> reused as Tpart[4][8][512][512] fp32.
    // Tf aliases Tpart[0] exactly (1:1 row mapping, write-after-read within block).
    // Mb/rs alias Tpart[1] (dead after softmax_col).
    u16*   xT    = (u16*)(ws);                   // 32 MB  [B][4096][512] bf16
    float* Tpart = (float*)(ws);                 // 32 MB  [4][B][512][512] fp32 (alias)
    float* Tf    = (float*)(ws);                 //  8 MB  (alias of Tpart[0])
    u16*   Mb    = (u16*)(ws + 8388608);         //  4 MB  [B][512][512] bf16 (alias)
    float* rs    = (float*)(ws + 12582912);      // 16 KB  (alias)
    u16*   Wb    = (u16*)(ws + 33554432);        // 1.5 MB [3][512][512] bf16
    float* rq    = (float*)(ws + 35127296);      // 16 KB
    float* rk    = (float*)(ws + 35143680);      // 16 KB
    u16*   Qb    = (u16*)(ws + 35160064);        // 32 MB  [B][512][4096] bf16
    u16*   Kb    = (u16*)(ws + 68714496);        // 32 MB
    u16*   VT    = (u16*)(ws + 102268928);       // 32 MB  [B][4096][512] bf16

    convw<<<3072, 256, 0, stream>>>(Wq, Wk, Wv, Wb);
    transpose_x<<<dim3(64, 8, 8), 256, 0, stream>>>(x, xT);
    qkv_mfma<<<dim3(32, 4, 24), 256, 0, stream>>>(Wb, xT, Qb, Kb, VT);
    rownorm<<<dim3(4096, 2), 256, 0, stream>>>(Qb, Kb, rq, rk);
    qk_part<<<dim3(4, 4, 32), 256, 0, stream>>>(Qb, Kb, Tpart);
    softmax_col<<<4096, 256, 0, stream>>>(Tpart, rq, rk, Tf);
    colsum<<<dim3(8, 2), 256, 0, stream>>>(Tf, rs);
    mscale<<<dim3(16, 16, 8), dim3(32, 8), 0, stream>>>(Tf, rs, Mb);
    out_mfma<<<dim3(32, 4, 8), 256, 0, stream>>>(Mb, VT, x, gamma, y);
}